// Round 5
// baseline (65.192 us; speedup 1.0000x reference)
//
#include <hip/hip_runtime.h>
#include <hip/hip_bf16.h>
#include <cmath>

// Problem constants (fixed by setup_inputs)
#define B_   16
#define H_   8
#define T_   196
#define DIM_ 512
#define DHEAD_ 64
#define TOPK_ 49
#define BT_  (B_ * T_)        // 3136
#define BH_  (B_ * H_)        // 128

// ws layout (ushort units)
#define QB_OFF   0u
#define KB_OFF   1605632u          // 128*196*64
#define VT_OFF   3211264u          // vT: [128][64][224]
#define XB_OFF   5046272u          // x bf16 [3136][512]; reused as o bf16
#define WQKVT_OFF 6651904u         // [1536][512]
#define WVT_OFF  7438336u          // [512][512]
#define MASK_OFF 7700480u          // (uint*) [25088][8]

// route queries handled inside prep dispatch (rest go in gemm1 dispatch)
#define QSPLIT_BLOCKS 3584         // x4 queries = 14336 (prep has memory headroom)

typedef __bf16 bf16x8 __attribute__((ext_vector_type(8)));
typedef float f32x4 __attribute__((ext_vector_type(4)));

__device__ __forceinline__ unsigned short f2bf(float f) {
    union { float f; unsigned int u; } v; v.f = f;
    const unsigned int u = v.u;
    return (unsigned short)((u + 0x7FFFu + ((u >> 16) & 1u)) >> 16);  // RNE
}

__device__ __forceinline__ unsigned int ordered_u32(float f) {
    int i = __float_as_int(f);
    return (i < 0) ? ~(unsigned int)i : ((unsigned int)i | 0x80000000u);
}

// async global->LDS, 16B per lane; lds dest = wave-uniform base + lane*16
__device__ __forceinline__ void gload16(const void* g, void* l) {
    __builtin_amdgcn_global_load_lds(
        (const __attribute__((address_space(1))) unsigned int*)g,
        (__attribute__((address_space(3))) unsigned int*)l, 16, 0, 0);
}

// exact top-49 per query via radix select over ordered-u32; one wave per query.
__device__ __forceinline__ void route_topk_q(const float* __restrict__ adj,
                                             unsigned int* __restrict__ masks,
                                             const int q, const int lane) {
    const float* arow = adj + (size_t)q * T_;
    const bool v3 = (lane < 4);
    unsigned int u[4];
    u[0] = ordered_u32(arow[lane]);
    u[1] = ordered_u32(arow[lane + 64]);
    u[2] = ordered_u32(arow[lane + 128]);
    u[3] = v3 ? ordered_u32(arow[lane + 192]) : 0u;

    unsigned int w0 = u[0], w1 = u[1], w2 = u[2], w3 = u[3];
    unsigned int prefix = 0u, thr = 0u;
    int k = TOPK_, A = T_;
    for (int b = 31; b >= 0; --b) {
        int C1 = 0;
        C1 += __popcll(__ballot((w0 >> b) == 1u));
        C1 += __popcll(__ballot((w1 >> b) == 1u));
        C1 += __popcll(__ballot((w2 >> b) == 1u));
        C1 += __popcll(__ballot((w3 >> b) == 1u));
        if (C1 >= k) {
            const unsigned int bit = 1u << b;
            prefix |= bit;
            w0 ^= bit; w1 ^= bit; w2 ^= bit; w3 ^= bit;
            A = C1;
        } else { k -= C1; A -= C1; }

        if (k == A || k == 1) {
            const bool mx = (k == 1);
            unsigned int best = mx ? 0u : 0xFFFFFFFFu;
            const unsigned int ww[4] = {w0, w1, w2, w3};
#pragma unroll
            for (int s2 = 0; s2 < 4; ++s2) {
                const bool valid = (s2 < 3) || v3;
                const bool act = valid && ((ww[s2] >> b) == 0u);
                if (act) best = mx ? (u[s2] > best ? u[s2] : best)
                                   : (u[s2] < best ? u[s2] : best);
            }
#pragma unroll
            for (int off = 32; off >= 1; off >>= 1) {
                const unsigned int o = __shfl_xor(best, off);
                best = mx ? (o > best ? o : best) : (o < best ? o : best);
            }
            thr = best;
            break;
        }
        if (b == 0) thr = prefix;
    }

    const unsigned long long lmask = (1ull << lane) - 1ull;
    unsigned long long gm[4];
    int G = 0;
#pragma unroll
    for (int s2 = 0; s2 < 4; ++s2) {
        const bool valid = (s2 < 3) || v3;
        gm[s2] = __ballot(valid && (u[s2] > thr));
        G += __popcll(gm[s2]);
    }
    const int need = TOPK_ - G;
    int cum = 0;
    unsigned long long sb0 = 0, sb1 = 0, sb2 = 0, sb3 = 0;
#pragma unroll
    for (int s2 = 0; s2 < 4; ++s2) {
        const bool valid = (s2 < 3) || v3;
        const bool e = valid && (u[s2] == thr);
        const unsigned long long em = __ballot(e);
        const int rk = cum + __popcll(em & lmask);
        cum += __popcll(em);
        const unsigned long long sel = gm[s2] | __ballot(e && (rk < need));
        if (s2 == 0) sb0 = sel; else if (s2 == 1) sb1 = sel;
        else if (s2 == 2) sb2 = sel; else sb3 = sel;
    }
    if (lane < 8) {
        const unsigned long long mv = (lane < 2) ? sb0 : (lane < 4) ? sb1
                                    : (lane < 6) ? sb2 : sb3;
        const unsigned int wd = (lane & 1) ? (unsigned int)(mv >> 32) : (unsigned int)mv;
        masks[(size_t)q * 8 + lane] = wd;
    }
}

// ---------------------------------------------------------------------------
// prep: VALU-bound route overlapped with memory-bound conversions.
//   blocks 0..3583      : top-49 route, queries 0..14335 (4/block, 1 wave ea)
//   next 784            : x fp32 -> bf16
//   next 192            : Wqkv -> WqkvT bf16 [1536][512]
//   next 28             : zero vT pad cols t=196..223
//   next 64             : Wv -> WvT bf16 [512][512]
// ---------------------------------------------------------------------------
__global__ __launch_bounds__(256) void prep(const float* __restrict__ x,
                                            const float* __restrict__ Wqkv,
                                            const float* __restrict__ Wv,
                                            const float* __restrict__ adj,
                                            unsigned short* __restrict__ xb,
                                            unsigned short* __restrict__ wqkvT,
                                            unsigned short* __restrict__ wvT,
                                            unsigned short* __restrict__ vT,
                                            unsigned int* __restrict__ masks) {
    __shared__ unsigned short Tt[64][72];
    const int t = threadIdx.x;
    const int bid = blockIdx.x;

    if (bid < QSPLIT_BLOCKS) {
        route_topk_q(adj, masks, bid * 4 + (t >> 6), t & 63);
        return;
    }
    int b2 = bid - QSPLIT_BLOCKS;
    if (b2 < 784) {
        const size_t base = ((size_t)b2 * 256 + t) * 8;
        const float4 v0 = *(const float4*)&x[base];
        const float4 v1 = *(const float4*)&x[base + 4];
        uint4 pk;
        pk.x = (unsigned int)f2bf(v0.x) | ((unsigned int)f2bf(v0.y) << 16);
        pk.y = (unsigned int)f2bf(v0.z) | ((unsigned int)f2bf(v0.w) << 16);
        pk.z = (unsigned int)f2bf(v1.x) | ((unsigned int)f2bf(v1.y) << 16);
        pk.w = (unsigned int)f2bf(v1.z) | ((unsigned int)f2bf(v1.w) << 16);
        *(uint4*)&xb[base] = pk;
        return;
    }
    b2 -= 784;
    if (b2 >= 192 && b2 < 220) {
        // zero vT pad cols t=196..223
        const int e0 = (b2 - 192) * 8192 + t;
#pragma unroll
        for (int i = 0; i < 32; ++i) {
            const int e = e0 + i * 256;          // 0..229375
            const int bh = e / 1792;             // 64*28
            const int rem = e - bh * 1792;
            const int d = rem / 28;
            const int tt = rem - d * 28;
            vT[(size_t)bh * (64 * 224) + (size_t)d * 224 + 196 + tt] = 0;
        }
        return;
    }

    // weight transposes via 64x64 LDS tile
    const float* src;
    unsigned short* dst;
    int Cc, tx, ty;
    if (b2 < 192) { src = Wqkv; dst = wqkvT; Cc = 1536; tx = b2 % 24; ty = b2 / 24; }
    else { const int b = b2 - 220; src = Wv; dst = wvT; Cc = 512; tx = b & 7; ty = b >> 3; }
    const int c0 = tx * 64, r0 = ty * 64;
#pragma unroll
    for (int p = 0; p < 4; ++p) {
        const int r = (t >> 4) + 16 * p;
        const int cl = (t & 15) * 4;
        const float4 v = *(const float4*)&src[(size_t)(r0 + r) * Cc + c0 + cl];
        Tt[cl + 0][r] = f2bf(v.x);
        Tt[cl + 1][r] = f2bf(v.y);
        Tt[cl + 2][r] = f2bf(v.z);
        Tt[cl + 3][r] = f2bf(v.w);
    }
    __syncthreads();
#pragma unroll
    for (int p = 0; p < 2; ++p) {
        const int cc = (t >> 3) + 32 * p;
        const int ch = (t & 7) * 8;
        *(uint4*)&dst[(size_t)(c0 + cc) * 512 + r0 + ch] = *(const uint4*)&Tt[cc][ch];
    }
}

// ---------------------------------------------------------------------------
// bf16 MFMA GEMM: C(MxN) = A(MxK) @ Bt(NxK)^T, fp32 accumulate.
// BM=64; 256 threads = 4 waves (2x2). Double-buffered global_load_lds.
// BN=64 for gemm1 -> 1176 blocks (4.6/CU): latency regime favors wave count
// over per-wave ILP. MODE 0: fp32 store. MODE 1: bf16 scatter to q/k/vT.
// FUSE 1: trailing 2688 blocks run top-49 route for queries 14336..25087.
// ---------------------------------------------------------------------------
template <int BN, int MODE, int FUSE, typename CT>
__global__ __launch_bounds__(256) void gemm_mfma(const unsigned short* __restrict__ A,
                                                 const unsigned short* __restrict__ Bt,
                                                 CT* __restrict__ C,
                                                 const int M, const int N, const int K,
                                                 const float* __restrict__ adj,
                                                 unsigned int* __restrict__ masks) {
    constexpr int FN = BN / 32;
    constexpr int CSZ = (MODE == 1) ? 64 * 132 : 1;
    struct ABt { unsigned short A[64][32]; unsigned short B[BN][32]; };
    __shared__ union {
        ABt ab[2];
        unsigned short Cs[CSZ];
    } sm;

    const int tid = threadIdx.x;
    const int lane = tid & 63, wid = tid >> 6;
    const int mt = M >> 6;
    const int nGemm = mt * (N / BN);
    const int bid = blockIdx.x;

    if constexpr (FUSE) {
        if (bid >= nGemm) {
            const int rid = bid - nGemm;
            route_topk_q(adj, masks, QSPLIT_BLOCKS * 4 + rid * 4 + wid, lane);
            return;
        }
    }

    const int bx = bid % mt;          // consecutive blocks share the B panel
    const int by = bid / mt;
    const int row0 = bx * 64;
    const int col0 = by * BN;
    const int wr = wid >> 1, wc = wid & 1;

    f32x4 acc[2][FN];
#pragma unroll
    for (int m = 0; m < 2; ++m)
#pragma unroll
        for (int n = 0; n < FN; ++n)
            acc[m][n] = (f32x4){0.0f, 0.0f, 0.0f, 0.0f};

    // per-lane staging sources: lane l covers row wid*16 + l/4, col (l%4)*8
    const int srow = lane >> 2;
    const int scol = (lane & 3) * 8;
    const unsigned short* aSrc = A + (size_t)(row0 + wid * 16 + srow) * K + scol;
    const unsigned short* bSrc = Bt + (size_t)(col0 + wid * 16 + srow) * K + scol;
    const unsigned short* bSrc2 = bSrc + (size_t)64 * K;

    const int fr = lane & 15;
    const int fk8 = (lane >> 4) * 8;

#define STAGE(BUF) do {                                                        \
        gload16(aSrc, &sm.ab[BUF].A[wid * 16][0]);                             \
        gload16(bSrc, &sm.ab[BUF].B[wid * 16][0]);                             \
        if constexpr (BN == 128) gload16(bSrc2, &sm.ab[BUF].B[64 + wid * 16][0]); \
        aSrc += 32; bSrc += 32; bSrc2 += 32;                                   \
    } while (0)

#define COMPUTE(BUF) do {                                                      \
        bf16x8 af[2], bfv[FN];                                                 \
        _Pragma("unroll")                                                      \
        for (int m = 0; m < 2; ++m)                                            \
            af[m] = *(const bf16x8*)&sm.ab[BUF].A[wr * 32 + m * 16 + fr][fk8]; \
        _Pragma("unroll")                                                      \
        for (int n = 0; n < FN; ++n)                                           \
            bfv[n] = *(const bf16x8*)&sm.ab[BUF].B[wc * (BN / 2) + n * 16 + fr][fk8]; \
        _Pragma("unroll")                                                      \
        for (int m = 0; m < 2; ++m)                                            \
            _Pragma("unroll")                                                  \
            for (int n = 0; n < FN; ++n)                                       \
                acc[m][n] = __builtin_amdgcn_mfma_f32_16x16x32_bf16(af[m], bfv[n], acc[m][n], 0, 0, 0); \
    } while (0)

    STAGE(0);
    __syncthreads();

    for (int k0 = 0; k0 < K; k0 += 64) {
        if (k0 + 32 < K) STAGE(1);
        COMPUTE(0);
        __syncthreads();
        if (k0 + 64 < K) STAGE(0);
        COMPUTE(1);
        __syncthreads();
    }
#undef STAGE
#undef COMPUTE

    if constexpr (MODE == 0) {
#pragma unroll
        for (int m = 0; m < 2; ++m)
#pragma unroll
            for (int n = 0; n < FN; ++n)
#pragma unroll
                for (int i = 0; i < 4; ++i) {
                    const int row = row0 + wr * 32 + m * 16 + (lane >> 4) * 4 + i;
                    const int col = col0 + wc * (BN / 2) + n * 16 + (lane & 15);
                    C[(size_t)row * N + col] = (CT)acc[m][n][i];
                }
    } else {
        // ---- stage tile to LDS as bf16 (Cs overlays ab; safe after barrier) ----
#pragma unroll
        for (int m = 0; m < 2; ++m)
#pragma unroll
            for (int n = 0; n < FN; ++n)
#pragma unroll
                for (int i = 0; i < 4; ++i) {
                    const int rl = wr * 32 + m * 16 + (lane >> 4) * 4 + i;
                    const int cl = wc * (BN / 2) + n * 16 + (lane & 15);
                    sm.Cs[rl * 132 + cl] = f2bf(acc[m][n][i]);
                }
        __syncthreads();

        unsigned short* ubase = (unsigned short*)C;
#pragma unroll
        for (int ch = 0; ch < BN / 64; ++ch) {
            const int abscol = col0 + ch * 64;
            const int which = (abscol >> 6) % 3;
            const int hh = abscol / 192;
            if (which < 2) {
                // q/k: row-major [bh][196][64]; thread = (row, 16-col chunk)
                const int r = tid >> 2;
                const int co = (tid & 3) * 16;
                const int gr = row0 + r;
                const int bb = gr / T_;
                const int tt = gr - bb * T_;
                const uint2 a0 = *(const uint2*)&sm.Cs[r * 132 + ch * 64 + co];
                const uint2 a1 = *(const uint2*)&sm.Cs[r * 132 + ch * 64 + co + 4];
                const uint2 a2 = *(const uint2*)&sm.Cs[r * 132 + ch * 64 + co + 8];
                const uint2 a3 = *(const uint2*)&sm.Cs[r * 132 + ch * 64 + co + 12];
                unsigned short* dst = ubase + (size_t)which * KB_OFF +
                                      ((size_t)(bb * H_ + hh) * T_ + tt) * DHEAD_ + co;
                uint4 w0; w0.x = a0.x; w0.y = a0.y; w0.z = a1.x; w0.w = a1.y;
                uint4 w1; w1.x = a2.x; w1.y = a2.y; w1.z = a3.x; w1.w = a3.y;
                *(uint4*)&dst[0] = w0;
                *(uint4*)&dst[8] = w1;
            } else {
                // v: d-major [bh][64][224]; thread = (d, 16-row span)
                const int d = tid >> 2;
                const int j0 = (tid & 3) * 16;
                union { unsigned short s[16]; uint2 v2[4]; } tmp;
#pragma unroll
                for (int j = 0; j < 16; ++j)
                    tmp.s[j] = sm.Cs[(j0 + j) * 132 + ch * 64 + d];
                const int gr0 = row0 + j0;
                const int bb0 = gr0 / T_;
                const int bb1 = (gr0 + 15) / T_;
                if (bb0 == bb1) {
                    const int tt = gr0 - bb0 * T_;   // tt % 4 == 0 -> 8B aligned
                    unsigned short* dst = ubase + VT_OFF +
                                          (size_t)(bb0 * H_ + hh) * (64 * 224) +
                                          (size_t)d * 224 + tt;
                    *(uint2*)&dst[0]  = tmp.v2[0];
                    *(uint2*)&dst[4]  = tmp.v2[1];
                    *(uint2*)&dst[8]  = tmp.v2[2];
                    *(uint2*)&dst[12] = tmp.v2[3];
                } else {
#pragma unroll
                    for (int j = 0; j < 16; ++j) {
                        const int gr = gr0 + j;
                        const int bb = gr / T_;
                        const int tt = gr - bb * T_;
                        ubase[VT_OFF + (size_t)(bb * H_ + hh) * (64 * 224) +
                              (size_t)d * 224 + tt] = tmp.s[j];
                    }
                }
            }
        }
    }
}

// ---------------------------------------------------------------------------
// attn_mfma: dense masked attention. One 16-query tile per 256-thread block;
// the 13 key-chunks are SPLIT ACROSS THE 4 WAVES (4/3/3/3). Spill-free,
// grid (13,128)=1664 blocks = 6656 waves.
// ---------------------------------------------------------------------------
__global__ __launch_bounds__(256, 4) void attn_mfma(const unsigned short* __restrict__ qb,
                                                    const unsigned short* __restrict__ kb,
                                                    const unsigned short* __restrict__ vT,
                                                    const unsigned int* __restrict__ masks,
                                                    unsigned short* __restrict__ obuf) {
    __shared__ union {
        struct { unsigned int mask[16][8]; unsigned short P[4][16][72]; } p1;
        struct { float Of[4][16][64]; float Lw[4][16]; } p2;
    } sm;

    const int tid = threadIdx.x;
    const int lane = tid & 63;
    const int w = tid >> 6;                 // wave 0..3
    const int qt = blockIdx.x;              // 0..12 (16-row tiles; tile 12: 4 valid)
    const int bh = blockIdx.y;              // 0..127
    const int bb = bh >> 3, hh = bh & 7;
    const int q0 = qt * 16;

    // masks (128 words) + zero own P[w][16][0..64)
    if (tid < 128) {
        const int r = tid >> 3, wd = tid & 7;
        const int t = q0 + r;
        sm.p1.mask[r][wd] = (t < T_) ? masks[((size_t)bh * T_ + t) * 8 + wd] : 0u;
    }
    {
        unsigned short* Pw = &sm.p1.P[w][0][0];
        const int r = lane >> 2, c = (lane & 3) * 16;
        *(uint4*)&Pw[r * 72 + c]     = (uint4){0u, 0u, 0u, 0u};
        *(uint4*)&Pw[r * 72 + c + 8] = (uint4){0u, 0u, 0u, 0u};
    }
    __syncthreads();

    const int fr = lane & 15;
    const int fk8 = (lane >> 4) * 8;
    const int nc = (w == 0) ? 4 : 3;
    const int cbase = (w == 0) ? 0 : 1 + 3 * w;     // 0,4,7,10
    const int keybase = cbase * 16;                  // 0,64,112,160

    const unsigned short* qbh = qb + ((size_t)bh * T_ + q0) * DHEAD_;
    const unsigned short* kbh = kb + (size_t)bh * T_ * DHEAD_;

    const bf16x8 aq0 = *(const bf16x8*)&qbh[fr * 64 + fk8];
    const bf16x8 aq1 = *(const bf16x8*)&qbh[fr * 64 + 32 + fk8];

    f32x4 s[4];
#pragma unroll
    for (int c2 = 0; c2 < 4; ++c2) s[c2] = (f32x4){0.0f, 0.0f, 0.0f, 0.0f};
    __builtin_amdgcn_s_setprio(1);
#pragma unroll
    for (int c2 = 0; c2 < 4; ++c2) {
        if (c2 < nc) {
            const int c = cbase + c2;
            const bf16x8 b0 = *(const bf16x8*)&kbh[(c * 16 + fr) * 64 + fk8];
            const bf16x8 b1 = *(const bf16x8*)&kbh[(c * 16 + fr) * 64 + 32 + fk8];
            s[c2] = __builtin_amdgcn_mfma_f32_16x16x32_bf16(aq0, b0, s[c2], 0, 0, 0);
            s[c2] = __builtin_amdgcn_mfma_f32_16x16x32_bf16(aq1, b1, s[c2], 0, 0, 0);
        }
    }
    __builtin_amdgcn_s_setprio(0);

    const float scale = 0.044194173824159216f;     // 512^-0.5
    float lv[4];
#pragma unroll
    for (int i = 0; i < 4; ++i) {
        const int rowl = (lane >> 4) * 4 + i;
        float li = 0.0f;
#pragma unroll
        for (int c2 = 0; c2 < 4; ++c2) {
            if (c2 < nc) {
                const int c = cbase + c2;
                const unsigned int mw = sm.p1.mask[rowl][c >> 1];
                const bool sel = (mw >> (((c & 1) << 4) + fr)) & 1u;
                const float pv = sel ? __expf(s[c2][i] * scale) : 0.0f;
                sm.p1.P[w][rowl][c2 * 16 + fr] = f2bf(pv);
                li += pv;
            }
        }
        lv[i] = li;
    }
#pragma unroll
    for (int off = 8; off >= 1; off >>= 1)
#pragma unroll
        for (int i = 0; i < 4; ++i)
            lv[i] += __shfl_xor(lv[i], off);

    // partial PV over this wave's 64-key window (keys beyond real range have P=0;
    // vT cols 196..223 are zeroed, window max col = keybase+63 <= 223)
    const unsigned short* vbh = vT + (size_t)bh * (64 * 224) + keybase;
    f32x4 o_p[4];
#pragma unroll
    for (int n = 0; n < 4; ++n) o_p[n] = (f32x4){0.0f, 0.0f, 0.0f, 0.0f};
    const bf16x8 ap0 = *(const bf16x8*)&sm.p1.P[w][fr][fk8];
    const bf16x8 ap1 = *(const bf16x8*)&sm.p1.P[w][fr][32 + fk8];
    __builtin_amdgcn_s_setprio(1);
#pragma unroll
    for (int n = 0; n < 4; ++n) {
        const bf16x8 bv0 = *(const bf16x8*)&vbh[(n * 16 + fr) * 224 + fk8];
        const bf16x8 bv1 = *(const bf16x8*)&vbh[(n * 16 + fr) * 224 + 32 + fk8];
        o_p[n] = __builtin_amdgcn_mfma_f32_16x16x32_bf16(ap0, bv0, o_p[n], 0, 0, 0);
        o_p[n] = __builtin_amdgcn_mfma_f32_16x16x32_bf16(ap1, bv1, o_p[n], 0, 0, 0);
    }
    __builtin_amdgcn_s_setprio(0);

    __syncthreads();   // all P reads done; safe to overwrite phase-1 LDS

    // write partial O (f32) + partial l
#pragma unroll
    for (int n = 0; n < 4; ++n)
#pragma unroll
        for (int i = 0; i < 4; ++i)
            sm.p2.Of[w][(lane >> 4) * 4 + i][n * 16 + fr] = o_p[n][i];
    if (fr == 0) {
#pragma unroll
        for (int i = 0; i < 4; ++i)
            sm.p2.Lw[w][(lane >> 4) * 4 + i] = lv[i];
    }
    __syncthreads();

    // combine + normalize + GELU + store: thread = (row, 4-col chunk)
    {
        const int r = tid >> 4;
        const int c0 = (tid & 15) * 4;
        const int t = q0 + r;
        if (t < T_) {
            const float l = sm.p2.Lw[0][r] + sm.p2.Lw[1][r] +
                            sm.p2.Lw[2][r] + sm.p2.Lw[3][r];
            const float rl = 1.0f / l;
            const f32x4 a0 = *(const f32x4*)&sm.p2.Of[0][r][c0];
            const f32x4 a1 = *(const f32x4*)&sm.p2.Of[1][r][c0];
            const f32x4 a2 = *(const f32x4*)&sm.p2.Of[2][r][c0];
            const f32x4 a3 = *(const f32x4*)&sm.p2.Of[3][r][c0];
            union { unsigned short s[4]; unsigned long long u; } pk;
#pragma unroll
            for (int j = 0; j < 4; ++j) {
                const float ov = (a0[j] + a1[j] + a2[j] + a3[j]) * rl;
                const float g = 0.5f * ov * (1.0f + erff(ov * 0.70710678118654752f));
                pk.s[j] = f2bf(g);
            }
            unsigned short* orow = obuf + ((size_t)(bb * T_ + t)) * DIM_ +
                                   hh * DHEAD_ + c0;
            *(unsigned long long*)orow = pk.u;
        }
    }
}

extern "C" void kernel_launch(void* const* d_in, const int* in_sizes, int n_in,
                              void* d_out, int out_size, void* d_ws, size_t ws_size,
                              hipStream_t stream) {
    const float* x    = (const float*)d_in[0];
    const float* adj  = (const float*)d_in[1];
    const float* Wqkv = (const float*)d_in[2];
    const float* Wv   = (const float*)d_in[3];
    float* out = (float*)d_out;
    unsigned short* ub = (unsigned short*)d_ws;

    unsigned short* qb    = ub + QB_OFF;
    unsigned short* kb    = ub + KB_OFF;
    unsigned short* vT    = ub + VT_OFF;
    unsigned short* xb    = ub + XB_OFF;      // x bf16; reused as o bf16
    unsigned short* wqkvT = ub + WQKVT_OFF;
    unsigned short* wvT   = ub + WVT_OFF;
    unsigned int*   masks = (unsigned int*)(ub + MASK_OFF);

    // 0) route queries 0..14335 (VALU) + x/Wqkv/Wv conversions (memory) + vT pad
    //    grid = 3584 + 784 + 192 + 28 + 64 = 4652
    prep<<<4652, 256, 0, stream>>>(x, Wqkv, Wv, adj, xb, wqkvT, wvT, vT, masks);

    // 1) qkv = x @ Wqkv (BN=64: 24 panels x 49 tiles = 1176 blocks, 4.6/CU)
    //    fused with route queries 14336..25087: 1176 + 2688 = 3864
    gemm_mfma<64, 1, 1, unsigned short><<<3864, 256, 0, stream>>>(
        xb, wqkvT, ub, BT_, 3 * DIM_, DIM_, adj, masks);

    // 2) dense masked attention + gelu -> o bf16 (aliases xb); K-split 4-wave
    attn_mfma<<<dim3(13, BH_), 256, 0, stream>>>(qb, kb, vT, masks, xb);

    // 3) out = o @ Wv (double-buffered bf16 MFMA) -> fp32
    gemm_mfma<64, 0, 0, float><<<392, 256, 0, stream>>>(
        xb, wvT, out, BT_, DIM_, DIM_, nullptr, nullptr);
}

// Round 6
// 65.033 us; speedup vs baseline: 1.0024x; 1.0024x over previous
//
#include <hip/hip_runtime.h>
#include <hip/hip_bf16.h>
#include <cmath>

// Problem constants (fixed by setup_inputs)
#define B_   16
#define H_   8
#define T_   196
#define DIM_ 512
#define DHEAD_ 64
#define TOPK_ 49
#define BT_  (B_ * T_)        // 3136
#define BH_  (B_ * H_)        // 128

// ws layout (ushort units)
#define QB_OFF   0u
#define KB_OFF   1605632u          // 128*196*64
#define VT_OFF   3211264u          // vT: [128][64][224]
#define XB_OFF   5046272u          // x bf16 [3136][512]; reused as o bf16
#define WQKVT_OFF 6651904u         // [1536][512]
#define WVT_OFF  7438336u          // [512][512]
#define MASK_OFF 7700480u          // (uint*) [25088][8]

// route queries handled inside prep dispatch (rest go in gemm1 dispatch)
#define QSPLIT_BLOCKS 3136         // x4 queries = 12544
#define PREP_MEMBLKS  1068         // 784 xconv + 192 wqkvT + 28 pad + 64 wvT

typedef __bf16 bf16x8 __attribute__((ext_vector_type(8)));
typedef float f32x4 __attribute__((ext_vector_type(4)));

__device__ __forceinline__ unsigned short f2bf(float f) {
    union { float f; unsigned int u; } v; v.f = f;
    const unsigned int u = v.u;
    return (unsigned short)((u + 0x7FFFu + ((u >> 16) & 1u)) >> 16);  // RNE
}

__device__ __forceinline__ unsigned int ordered_u32(float f) {
    int i = __float_as_int(f);
    return (i < 0) ? ~(unsigned int)i : ((unsigned int)i | 0x80000000u);
}

// async global->LDS, 16B per lane; lds dest = wave-uniform base + lane*16
__device__ __forceinline__ void gload16(const void* g, void* l) {
    __builtin_amdgcn_global_load_lds(
        (const __attribute__((address_space(1))) unsigned int*)g,
        (__attribute__((address_space(3))) unsigned int*)l, 16, 0, 0);
}

// exact top-49 per query via radix select over ordered-u32; one wave per query.
__device__ __forceinline__ void route_topk_q(const float* __restrict__ adj,
                                             unsigned int* __restrict__ masks,
                                             const int q, const int lane) {
    const float* arow = adj + (size_t)q * T_;
    const bool v3 = (lane < 4);
    unsigned int u[4];
    u[0] = ordered_u32(arow[lane]);
    u[1] = ordered_u32(arow[lane + 64]);
    u[2] = ordered_u32(arow[lane + 128]);
    u[3] = v3 ? ordered_u32(arow[lane + 192]) : 0u;

    unsigned int w0 = u[0], w1 = u[1], w2 = u[2], w3 = u[3];
    unsigned int prefix = 0u, thr = 0u;
    int k = TOPK_, A = T_;
    for (int b = 31; b >= 0; --b) {
        int C1 = 0;
        C1 += __popcll(__ballot((w0 >> b) == 1u));
        C1 += __popcll(__ballot((w1 >> b) == 1u));
        C1 += __popcll(__ballot((w2 >> b) == 1u));
        C1 += __popcll(__ballot((w3 >> b) == 1u));
        if (C1 >= k) {
            const unsigned int bit = 1u << b;
            prefix |= bit;
            w0 ^= bit; w1 ^= bit; w2 ^= bit; w3 ^= bit;
            A = C1;
        } else { k -= C1; A -= C1; }

        if (k == A || k == 1) {
            const bool mx = (k == 1);
            unsigned int best = mx ? 0u : 0xFFFFFFFFu;
            const unsigned int ww[4] = {w0, w1, w2, w3};
#pragma unroll
            for (int s2 = 0; s2 < 4; ++s2) {
                const bool valid = (s2 < 3) || v3;
                const bool act = valid && ((ww[s2] >> b) == 0u);
                if (act) best = mx ? (u[s2] > best ? u[s2] : best)
                                   : (u[s2] < best ? u[s2] : best);
            }
#pragma unroll
            for (int off = 32; off >= 1; off >>= 1) {
                const unsigned int o = __shfl_xor(best, off);
                best = mx ? (o > best ? o : best) : (o < best ? o : best);
            }
            thr = best;
            break;
        }
        if (b == 0) thr = prefix;
    }

    const unsigned long long lmask = (1ull << lane) - 1ull;
    unsigned long long gm[4];
    int G = 0;
#pragma unroll
    for (int s2 = 0; s2 < 4; ++s2) {
        const bool valid = (s2 < 3) || v3;
        gm[s2] = __ballot(valid && (u[s2] > thr));
        G += __popcll(gm[s2]);
    }
    const int need = TOPK_ - G;
    int cum = 0;
    unsigned long long sb0 = 0, sb1 = 0, sb2 = 0, sb3 = 0;
#pragma unroll
    for (int s2 = 0; s2 < 4; ++s2) {
        const bool valid = (s2 < 3) || v3;
        const bool e = valid && (u[s2] == thr);
        const unsigned long long em = __ballot(e);
        const int rk = cum + __popcll(em & lmask);
        cum += __popcll(em);
        const unsigned long long sel = gm[s2] | __ballot(e && (rk < need));
        if (s2 == 0) sb0 = sel; else if (s2 == 1) sb1 = sel;
        else if (s2 == 2) sb2 = sel; else sb3 = sel;
    }
    if (lane < 8) {
        const unsigned long long mv = (lane < 2) ? sb0 : (lane < 4) ? sb1
                                    : (lane < 6) ? sb2 : sb3;
        const unsigned int wd = (lane & 1) ? (unsigned int)(mv >> 32) : (unsigned int)mv;
        masks[(size_t)q * 8 + lane] = wd;
    }
}

// ---------------------------------------------------------------------------
// prep: MEMORY BLOCKS FIRST (all co-resident immediately -> saturate HBM),
// route blocks after (backfill VALU while memory blocks wait on HBM).
//   blocks 0..783       : x fp32 -> bf16
//   blocks 784..975     : Wqkv -> WqkvT bf16 [1536][512]
//   blocks 976..1003    : zero vT pad cols t=196..223
//   blocks 1004..1067   : Wv -> WvT bf16 [512][512]
//   blocks 1068..4651   : top-49 route, queries 0..12543 (4/block)
// ---------------------------------------------------------------------------
__global__ __launch_bounds__(256) void prep(const float* __restrict__ x,
                                            const float* __restrict__ Wqkv,
                                            const float* __restrict__ Wv,
                                            const float* __restrict__ adj,
                                            unsigned short* __restrict__ xb,
                                            unsigned short* __restrict__ wqkvT,
                                            unsigned short* __restrict__ wvT,
                                            unsigned short* __restrict__ vT,
                                            unsigned int* __restrict__ masks) {
    __shared__ unsigned short Tt[64][72];
    const int t = threadIdx.x;
    const int bid = blockIdx.x;

    if (bid >= PREP_MEMBLKS) {
        route_topk_q(adj, masks, (bid - PREP_MEMBLKS) * 4 + (t >> 6), t & 63);
        return;
    }
    if (bid < 784) {
        const size_t base = ((size_t)bid * 256 + t) * 8;
        const float4 v0 = *(const float4*)&x[base];
        const float4 v1 = *(const float4*)&x[base + 4];
        uint4 pk;
        pk.x = (unsigned int)f2bf(v0.x) | ((unsigned int)f2bf(v0.y) << 16);
        pk.y = (unsigned int)f2bf(v0.z) | ((unsigned int)f2bf(v0.w) << 16);
        pk.z = (unsigned int)f2bf(v1.x) | ((unsigned int)f2bf(v1.y) << 16);
        pk.w = (unsigned int)f2bf(v1.z) | ((unsigned int)f2bf(v1.w) << 16);
        *(uint4*)&xb[base] = pk;
        return;
    }
    int b2 = bid - 784;      // 0..283
    if (b2 >= 192 && b2 < 220) {
        // zero vT pad cols t=196..223
        const int e0 = (b2 - 192) * 8192 + t;
#pragma unroll
        for (int i = 0; i < 32; ++i) {
            const int e = e0 + i * 256;          // 0..229375
            const int bh = e / 1792;             // 64*28
            const int rem = e - bh * 1792;
            const int d = rem / 28;
            const int tt = rem - d * 28;
            vT[(size_t)bh * (64 * 224) + (size_t)d * 224 + 196 + tt] = 0;
        }
        return;
    }

    // weight transposes via 64x64 LDS tile
    const float* src;
    unsigned short* dst;
    int Cc, tx, ty;
    if (b2 < 192) { src = Wqkv; dst = wqkvT; Cc = 1536; tx = b2 % 24; ty = b2 / 24; }
    else { const int b = b2 - 220; src = Wv; dst = wvT; Cc = 512; tx = b & 7; ty = b >> 3; }
    const int c0 = tx * 64, r0 = ty * 64;
#pragma unroll
    for (int p = 0; p < 4; ++p) {
        const int r = (t >> 4) + 16 * p;
        const int cl = (t & 15) * 4;
        const float4 v = *(const float4*)&src[(size_t)(r0 + r) * Cc + c0 + cl];
        Tt[cl + 0][r] = f2bf(v.x);
        Tt[cl + 1][r] = f2bf(v.y);
        Tt[cl + 2][r] = f2bf(v.z);
        Tt[cl + 3][r] = f2bf(v.w);
    }
    __syncthreads();
#pragma unroll
    for (int p = 0; p < 2; ++p) {
        const int cc = (t >> 3) + 32 * p;
        const int ch = (t & 7) * 8;
        *(uint4*)&dst[(size_t)(c0 + cc) * 512 + r0 + ch] = *(const uint4*)&Tt[cc][ch];
    }
}

// ---------------------------------------------------------------------------
// bf16 MFMA GEMM: C(MxN) = A(MxK) @ Bt(NxK)^T, fp32 accumulate.
// BM=64, BK=32; 256 threads = 4 waves (2x2). Double-buffered global_load_lds.
// XCD-chunked bijective block swizzle (T1): blocks sharing a B panel land on
// the same XCD's L2. MODE 0: fp32 store. MODE 1: bf16 scatter to q/k/vT.
// FUSE 1: trailing blocks run top-49 route for queries 12544..25087.
// ---------------------------------------------------------------------------
template <int BN, int MODE, int FUSE, typename CT>
__global__ __launch_bounds__(256) void gemm_mfma(const unsigned short* __restrict__ A,
                                                 const unsigned short* __restrict__ Bt,
                                                 CT* __restrict__ C,
                                                 const int M, const int N, const int K,
                                                 const float* __restrict__ adj,
                                                 unsigned int* __restrict__ masks) {
    constexpr int FN = BN / 32;
    constexpr int CSZ = (MODE == 1) ? 64 * 132 : 1;
    struct ABt { unsigned short A[64][32]; unsigned short B[BN][32]; };
    __shared__ union {
        ABt ab[2];
        unsigned short Cs[CSZ];
    } sm;

    const int tid = threadIdx.x;
    const int lane = tid & 63, wid = tid >> 6;
    const int mt = M >> 6;
    const int nGemm = mt * (N / BN);
    const int bid = blockIdx.x;

    if constexpr (FUSE) {
        if (bid >= nGemm) {
            const int rid = bid - nGemm;
            route_topk_q(adj, masks, QSPLIT_BLOCKS * 4 + rid * 4 + wid, lane);
            return;
        }
    }

    // XCD-chunked bijective swizzle (m204 variant): xcd = bid%8 keeps its
    // round-robin HW placement; work ids are contiguous per XCD.
    const int nx = nGemm >> 3, rr = nGemm & 7;
    const int xcd = bid & 7, base = bid >> 3;
    const int swz = (xcd < rr ? xcd * (nx + 1) : rr * (nx + 1) + (xcd - rr) * nx) + base;

    const int bx = swz % mt;          // consecutive work ids share the B panel
    const int by = swz / mt;
    const int row0 = bx * 64;
    const int col0 = by * BN;
    const int wr = wid >> 1, wc = wid & 1;

    f32x4 acc[2][FN];
#pragma unroll
    for (int m = 0; m < 2; ++m)
#pragma unroll
        for (int n = 0; n < FN; ++n)
            acc[m][n] = (f32x4){0.0f, 0.0f, 0.0f, 0.0f};

    // per-lane staging sources: lane l covers row wid*16 + l/4, col (l%4)*8
    const int srow = lane >> 2;
    const int scol = (lane & 3) * 8;
    const unsigned short* aSrc = A + (size_t)(row0 + wid * 16 + srow) * K + scol;
    const unsigned short* bSrc = Bt + (size_t)(col0 + wid * 16 + srow) * K + scol;
    const unsigned short* bSrc2 = bSrc + (size_t)64 * K;

    const int fr = lane & 15;
    const int fk8 = (lane >> 4) * 8;

#define STAGE(BUF) do {                                                        \
        gload16(aSrc, &sm.ab[BUF].A[wid * 16][0]);                             \
        gload16(bSrc, &sm.ab[BUF].B[wid * 16][0]);                             \
        if constexpr (BN == 128) gload16(bSrc2, &sm.ab[BUF].B[64 + wid * 16][0]); \
        aSrc += 32; bSrc += 32; bSrc2 += 32;                                   \
    } while (0)

#define COMPUTE(BUF) do {                                                      \
        bf16x8 af[2], bfv[FN];                                                 \
        _Pragma("unroll")                                                      \
        for (int m = 0; m < 2; ++m)                                            \
            af[m] = *(const bf16x8*)&sm.ab[BUF].A[wr * 32 + m * 16 + fr][fk8]; \
        _Pragma("unroll")                                                      \
        for (int n = 0; n < FN; ++n)                                           \
            bfv[n] = *(const bf16x8*)&sm.ab[BUF].B[wc * (BN / 2) + n * 16 + fr][fk8]; \
        _Pragma("unroll")                                                      \
        for (int m = 0; m < 2; ++m)                                            \
            _Pragma("unroll")                                                  \
            for (int n = 0; n < FN; ++n)                                       \
                acc[m][n] = __builtin_amdgcn_mfma_f32_16x16x32_bf16(af[m], bfv[n], acc[m][n], 0, 0, 0); \
    } while (0)

    STAGE(0);
    __syncthreads();

    for (int k0 = 0; k0 < K; k0 += 64) {
        if (k0 + 32 < K) STAGE(1);
        COMPUTE(0);
        __syncthreads();
        if (k0 + 64 < K) STAGE(0);
        COMPUTE(1);
        __syncthreads();
    }
#undef STAGE
#undef COMPUTE

    if constexpr (MODE == 0) {
#pragma unroll
        for (int m = 0; m < 2; ++m)
#pragma unroll
            for (int n = 0; n < FN; ++n)
#pragma unroll
                for (int i = 0; i < 4; ++i) {
                    const int row = row0 + wr * 32 + m * 16 + (lane >> 4) * 4 + i;
                    const int col = col0 + wc * (BN / 2) + n * 16 + (lane & 15);
                    C[(size_t)row * N + col] = (CT)acc[m][n][i];
                }
    } else {
        // ---- stage tile to LDS as bf16 (Cs overlays ab; safe after barrier) ----
#pragma unroll
        for (int m = 0; m < 2; ++m)
#pragma unroll
            for (int n = 0; n < FN; ++n)
#pragma unroll
                for (int i = 0; i < 4; ++i) {
                    const int rl = wr * 32 + m * 16 + (lane >> 4) * 4 + i;
                    const int cl = wc * (BN / 2) + n * 16 + (lane & 15);
                    sm.Cs[rl * 132 + cl] = f2bf(acc[m][n][i]);
                }
        __syncthreads();

        unsigned short* ubase = (unsigned short*)C;
#pragma unroll
        for (int ch = 0; ch < BN / 64; ++ch) {
            const int abscol = col0 + ch * 64;
            const int which = (abscol >> 6) % 3;
            const int hh = abscol / 192;
            if (which < 2) {
                // q/k: row-major [bh][196][64]; thread = (row, 16-col chunk)
                const int r = tid >> 2;
                const int co = (tid & 3) * 16;
                const int gr = row0 + r;
                const int bb = gr / T_;
                const int tt = gr - bb * T_;
                const uint2 a0 = *(const uint2*)&sm.Cs[r * 132 + ch * 64 + co];
                const uint2 a1 = *(const uint2*)&sm.Cs[r * 132 + ch * 64 + co + 4];
                const uint2 a2 = *(const uint2*)&sm.Cs[r * 132 + ch * 64 + co + 8];
                const uint2 a3 = *(const uint2*)&sm.Cs[r * 132 + ch * 64 + co + 12];
                unsigned short* dst = ubase + (size_t)which * KB_OFF +
                                      ((size_t)(bb * H_ + hh) * T_ + tt) * DHEAD_ + co;
                uint4 w0; w0.x = a0.x; w0.y = a0.y; w0.z = a1.x; w0.w = a1.y;
                uint4 w1; w1.x = a2.x; w1.y = a2.y; w1.z = a3.x; w1.w = a3.y;
                *(uint4*)&dst[0] = w0;
                *(uint4*)&dst[8] = w1;
            } else {
                // v: d-major [bh][64][224]; thread = (d, 16-row span)
                const int d = tid >> 2;
                const int j0 = (tid & 3) * 16;
                union { unsigned short s[16]; uint2 v2[4]; } tmp;
#pragma unroll
                for (int j = 0; j < 16; ++j)
                    tmp.s[j] = sm.Cs[(j0 + j) * 132 + ch * 64 + d];
                const int gr0 = row0 + j0;
                const int bb0 = gr0 / T_;
                const int bb1 = (gr0 + 15) / T_;
                if (bb0 == bb1) {
                    const int tt = gr0 - bb0 * T_;   // tt % 4 == 0 -> 8B aligned
                    unsigned short* dst = ubase + VT_OFF +
                                          (size_t)(bb0 * H_ + hh) * (64 * 224) +
                                          (size_t)d * 224 + tt;
                    *(uint2*)&dst[0]  = tmp.v2[0];
                    *(uint2*)&dst[4]  = tmp.v2[1];
                    *(uint2*)&dst[8]  = tmp.v2[2];
                    *(uint2*)&dst[12] = tmp.v2[3];
                } else {
#pragma unroll
                    for (int j = 0; j < 16; ++j) {
                        const int gr = gr0 + j;
                        const int bb = gr / T_;
                        const int tt = gr - bb * T_;
                        ubase[VT_OFF + (size_t)(bb * H_ + hh) * (64 * 224) +
                              (size_t)d * 224 + tt] = tmp.s[j];
                    }
                }
            }
        }
    }
}

// ---------------------------------------------------------------------------
// attn_mfma: dense masked attention. One 16-query tile per 256-thread block;
// 13 key-chunks SPLIT ACROSS THE 4 WAVES (4/3/3/3). 1-D grid 1664 = 8*208
// with XCD-chunked swizzle: 208 = 16*13 -> each XCD runs 16 complete bh
// groups, so each bh's K/V (53 KB) is fetched into ONE XCD's L2 and re-read
// there by its 13 blocks (was replicated ~8x across XCDs).
// ---------------------------------------------------------------------------
__global__ __launch_bounds__(256, 4) void attn_mfma(const unsigned short* __restrict__ qb,
                                                    const unsigned short* __restrict__ kb,
                                                    const unsigned short* __restrict__ vT,
                                                    const unsigned int* __restrict__ masks,
                                                    unsigned short* __restrict__ obuf) {
    __shared__ union {
        struct { unsigned int mask[16][8]; unsigned short P[4][16][72]; } p1;
        struct { float Of[4][16][64]; float Lw[4][16]; } p2;
    } sm;

    const int tid = threadIdx.x;
    const int lane = tid & 63;
    const int w = tid >> 6;                 // wave 0..3
    const int swz = (blockIdx.x & 7) * 208 + (blockIdx.x >> 3);
    const int qt = swz % 13;                // 0..12 (16-row tiles; tile 12: 4 valid)
    const int bh = swz / 13;                // 0..127
    const int bb = bh >> 3, hh = bh & 7;
    const int q0 = qt * 16;

    // masks (128 words) + zero own P[w][16][0..64)
    if (tid < 128) {
        const int r = tid >> 3, wd = tid & 7;
        const int t = q0 + r;
        sm.p1.mask[r][wd] = (t < T_) ? masks[((size_t)bh * T_ + t) * 8 + wd] : 0u;
    }
    {
        unsigned short* Pw = &sm.p1.P[w][0][0];
        const int r = lane >> 2, c = (lane & 3) * 16;
        *(uint4*)&Pw[r * 72 + c]     = (uint4){0u, 0u, 0u, 0u};
        *(uint4*)&Pw[r * 72 + c + 8] = (uint4){0u, 0u, 0u, 0u};
    }
    __syncthreads();

    const int fr = lane & 15;
    const int fk8 = (lane >> 4) * 8;
    const int nc = (w == 0) ? 4 : 3;
    const int cbase = (w == 0) ? 0 : 1 + 3 * w;     // 0,4,7,10
    const int keybase = cbase * 16;                  // 0,64,112,160

    const unsigned short* qbh = qb + ((size_t)bh * T_ + q0) * DHEAD_;
    const unsigned short* kbh = kb + (size_t)bh * T_ * DHEAD_;

    const bf16x8 aq0 = *(const bf16x8*)&qbh[fr * 64 + fk8];
    const bf16x8 aq1 = *(const bf16x8*)&qbh[fr * 64 + 32 + fk8];

    f32x4 s[4];
#pragma unroll
    for (int c2 = 0; c2 < 4; ++c2) s[c2] = (f32x4){0.0f, 0.0f, 0.0f, 0.0f};
    __builtin_amdgcn_s_setprio(1);
#pragma unroll
    for (int c2 = 0; c2 < 4; ++c2) {
        if (c2 < nc) {
            const int c = cbase + c2;
            const bf16x8 b0 = *(const bf16x8*)&kbh[(c * 16 + fr) * 64 + fk8];
            const bf16x8 b1 = *(const bf16x8*)&kbh[(c * 16 + fr) * 64 + 32 + fk8];
            s[c2] = __builtin_amdgcn_mfma_f32_16x16x32_bf16(aq0, b0, s[c2], 0, 0, 0);
            s[c2] = __builtin_amdgcn_mfma_f32_16x16x32_bf16(aq1, b1, s[c2], 0, 0, 0);
        }
    }
    __builtin_amdgcn_s_setprio(0);

    const float scale = 0.044194173824159216f;     // 512^-0.5
    float lv[4];
#pragma unroll
    for (int i = 0; i < 4; ++i) {
        const int rowl = (lane >> 4) * 4 + i;
        float li = 0.0f;
#pragma unroll
        for (int c2 = 0; c2 < 4; ++c2) {
            if (c2 < nc) {
                const int c = cbase + c2;
                const unsigned int mw = sm.p1.mask[rowl][c >> 1];
                const bool sel = (mw >> (((c & 1) << 4) + fr)) & 1u;
                const float pv = sel ? __expf(s[c2][i] * scale) : 0.0f;
                sm.p1.P[w][rowl][c2 * 16 + fr] = f2bf(pv);
                li += pv;
            }
        }
        lv[i] = li;
    }
#pragma unroll
    for (int off = 8; off >= 1; off >>= 1)
#pragma unroll
        for (int i = 0; i < 4; ++i)
            lv[i] += __shfl_xor(lv[i], off);

    // partial PV over this wave's 64-key window (keys beyond real range have P=0;
    // vT cols 196..223 are zeroed, window max col = keybase+63 <= 223)
    const unsigned short* vbh = vT + (size_t)bh * (64 * 224) + keybase;
    f32x4 o_p[4];
#pragma unroll
    for (int n = 0; n < 4; ++n) o_p[n] = (f32x4){0.0f, 0.0f, 0.0f, 0.0f};
    const bf16x8 ap0 = *(const bf16x8*)&sm.p1.P[w][fr][fk8];
    const bf16x8 ap1 = *(const bf16x8*)&sm.p1.P[w][fr][32 + fk8];
    __builtin_amdgcn_s_setprio(1);
#pragma unroll
    for (int n = 0; n < 4; ++n) {
        const bf16x8 bv0 = *(const bf16x8*)&vbh[(n * 16 + fr) * 224 + fk8];
        const bf16x8 bv1 = *(const bf16x8*)&vbh[(n * 16 + fr) * 224 + 32 + fk8];
        o_p[n] = __builtin_amdgcn_mfma_f32_16x16x32_bf16(ap0, bv0, o_p[n], 0, 0, 0);
        o_p[n] = __builtin_amdgcn_mfma_f32_16x16x32_bf16(ap1, bv1, o_p[n], 0, 0, 0);
    }
    __builtin_amdgcn_s_setprio(0);

    __syncthreads();   // all P reads done; safe to overwrite phase-1 LDS

    // write partial O (f32) + partial l
#pragma unroll
    for (int n = 0; n < 4; ++n)
#pragma unroll
        for (int i = 0; i < 4; ++i)
            sm.p2.Of[w][(lane >> 4) * 4 + i][n * 16 + fr] = o_p[n][i];
    if (fr == 0) {
#pragma unroll
        for (int i = 0; i < 4; ++i)
            sm.p2.Lw[w][(lane >> 4) * 4 + i] = lv[i];
    }
    __syncthreads();

    // combine + normalize + GELU + store: thread = (row, 4-col chunk)
    {
        const int r = tid >> 4;
        const int c0 = (tid & 15) * 4;
        const int t = q0 + r;
        if (t < T_) {
            const float l = sm.p2.Lw[0][r] + sm.p2.Lw[1][r] +
                            sm.p2.Lw[2][r] + sm.p2.Lw[3][r];
            const float rl = 1.0f / l;
            const f32x4 a0 = *(const f32x4*)&sm.p2.Of[0][r][c0];
            const f32x4 a1 = *(const f32x4*)&sm.p2.Of[1][r][c0];
            const f32x4 a2 = *(const f32x4*)&sm.p2.Of[2][r][c0];
            const f32x4 a3 = *(const f32x4*)&sm.p2.Of[3][r][c0];
            union { unsigned short s[4]; unsigned long long u; } pk;
#pragma unroll
            for (int j = 0; j < 4; ++j) {
                const float ov = (a0[j] + a1[j] + a2[j] + a3[j]) * rl;
                const float g = 0.5f * ov * (1.0f + erff(ov * 0.70710678118654752f));
                pk.s[j] = f2bf(g);
            }
            unsigned short* orow = obuf + ((size_t)(bb * T_ + t)) * DIM_ +
                                   hh * DHEAD_ + c0;
            *(unsigned long long*)orow = pk.u;
        }
    }
}

extern "C" void kernel_launch(void* const* d_in, const int* in_sizes, int n_in,
                              void* d_out, int out_size, void* d_ws, size_t ws_size,
                              hipStream_t stream) {
    const float* x    = (const float*)d_in[0];
    const float* adj  = (const float*)d_in[1];
    const float* Wqkv = (const float*)d_in[2];
    const float* Wv   = (const float*)d_in[3];
    float* out = (float*)d_out;
    unsigned short* ub = (unsigned short*)d_ws;

    unsigned short* qb    = ub + QB_OFF;
    unsigned short* kb    = ub + KB_OFF;
    unsigned short* vT    = ub + VT_OFF;
    unsigned short* xb    = ub + XB_OFF;      // x bf16; reused as o bf16
    unsigned short* wqkvT = ub + WQKVT_OFF;
    unsigned short* wvT   = ub + WVT_OFF;
    unsigned int*   masks = (unsigned int*)(ub + MASK_OFF);

    // 0) memory blocks first (1068), then route queries 0..12543 (3136 blocks)
    prep<<<4204, 256, 0, stream>>>(x, Wqkv, Wv, adj, xb, wqkvT, wvT, vT, masks);

    // 1) qkv = x @ Wqkv (BN=128: 588 blocks, XCD-swizzled) + route 12544..25087
    gemm_mfma<128, 1, 1, unsigned short><<<3724, 256, 0, stream>>>(
        xb, wqkvT, ub, BT_, 3 * DIM_, DIM_, adj, masks);

    // 2) dense masked attention + gelu -> o bf16 (aliases xb); XCD-swizzled 1-D
    attn_mfma<<<1664, 256, 0, stream>>>(qb, kb, vT, masks, xb);

    // 3) out = o @ Wv (392 = 8x49 blocks: each XCD owns one wvT panel)
    gemm_mfma<64, 0, 0, float><<<392, 256, 0, stream>>>(
        xb, wvT, out, BT_, DIM_, DIM_, nullptr, nullptr);
}

// Round 7
// 62.250 us; speedup vs baseline: 1.0473x; 1.0447x over previous
//
#include <hip/hip_runtime.h>
#include <hip/hip_bf16.h>
#include <cmath>

// Problem constants (fixed by setup_inputs)
#define B_   16
#define H_   8
#define T_   196
#define DIM_ 512
#define DHEAD_ 64
#define TOPK_ 49
#define BT_  (B_ * T_)        // 3136
#define BH_  (B_ * H_)        // 128

// ws layout (ushort units)
#define QB_OFF   0u
#define KB_OFF   1605632u          // 128*196*64
#define VT_OFF   3211264u          // vT: [128][64][224]
#define XB_OFF   5046272u          // x bf16 [3136][512]; reused as o bf16
#define WQKVT_OFF 6651904u         // [1536][512]
#define WVT_OFF  7438336u          // [512][512]
#define MASK_OFF 7700480u          // (uint*) [25088][8]

// route queries handled inside prep dispatch (rest go in gemm1 dispatch)
#define QSPLIT_BLOCKS 3136         // x4 queries = 12544

typedef __bf16 bf16x8 __attribute__((ext_vector_type(8)));
typedef float f32x4 __attribute__((ext_vector_type(4)));

__device__ __forceinline__ unsigned short f2bf(float f) {
    union { float f; unsigned int u; } v; v.f = f;
    const unsigned int u = v.u;
    return (unsigned short)((u + 0x7FFFu + ((u >> 16) & 1u)) >> 16);  // RNE
}

__device__ __forceinline__ unsigned int ordered_u32(float f) {
    int i = __float_as_int(f);
    return (i < 0) ? ~(unsigned int)i : ((unsigned int)i | 0x80000000u);
}

// async global->LDS, 16B per lane; lds dest = wave-uniform base + lane*16
__device__ __forceinline__ void gload16(const void* g, void* l) {
    __builtin_amdgcn_global_load_lds(
        (const __attribute__((address_space(1))) unsigned int*)g,
        (__attribute__((address_space(3))) unsigned int*)l, 16, 0, 0);
}

// exact top-49 per query via radix select over ordered-u32; one wave per query.
__device__ __forceinline__ void route_topk_q(const float* __restrict__ adj,
                                             unsigned int* __restrict__ masks,
                                             const int q, const int lane) {
    const float* arow = adj + (size_t)q * T_;
    const bool v3 = (lane < 4);
    unsigned int u[4];
    u[0] = ordered_u32(arow[lane]);
    u[1] = ordered_u32(arow[lane + 64]);
    u[2] = ordered_u32(arow[lane + 128]);
    u[3] = v3 ? ordered_u32(arow[lane + 192]) : 0u;

    unsigned int w0 = u[0], w1 = u[1], w2 = u[2], w3 = u[3];
    unsigned int prefix = 0u, thr = 0u;
    int k = TOPK_, A = T_;
    for (int b = 31; b >= 0; --b) {
        int C1 = 0;
        C1 += __popcll(__ballot((w0 >> b) == 1u));
        C1 += __popcll(__ballot((w1 >> b) == 1u));
        C1 += __popcll(__ballot((w2 >> b) == 1u));
        C1 += __popcll(__ballot((w3 >> b) == 1u));
        if (C1 >= k) {
            const unsigned int bit = 1u << b;
            prefix |= bit;
            w0 ^= bit; w1 ^= bit; w2 ^= bit; w3 ^= bit;
            A = C1;
        } else { k -= C1; A -= C1; }

        if (k == A || k == 1) {
            const bool mx = (k == 1);
            unsigned int best = mx ? 0u : 0xFFFFFFFFu;
            const unsigned int ww[4] = {w0, w1, w2, w3};
#pragma unroll
            for (int s2 = 0; s2 < 4; ++s2) {
                const bool valid = (s2 < 3) || v3;
                const bool act = valid && ((ww[s2] >> b) == 0u);
                if (act) best = mx ? (u[s2] > best ? u[s2] : best)
                                   : (u[s2] < best ? u[s2] : best);
            }
#pragma unroll
            for (int off = 32; off >= 1; off >>= 1) {
                const unsigned int o = __shfl_xor(best, off);
                best = mx ? (o > best ? o : best) : (o < best ? o : best);
            }
            thr = best;
            break;
        }
        if (b == 0) thr = prefix;
    }

    const unsigned long long lmask = (1ull << lane) - 1ull;
    unsigned long long gm[4];
    int G = 0;
#pragma unroll
    for (int s2 = 0; s2 < 4; ++s2) {
        const bool valid = (s2 < 3) || v3;
        gm[s2] = __ballot(valid && (u[s2] > thr));
        G += __popcll(gm[s2]);
    }
    const int need = TOPK_ - G;
    int cum = 0;
    unsigned long long sb0 = 0, sb1 = 0, sb2 = 0, sb3 = 0;
#pragma unroll
    for (int s2 = 0; s2 < 4; ++s2) {
        const bool valid = (s2 < 3) || v3;
        const bool e = valid && (u[s2] == thr);
        const unsigned long long em = __ballot(e);
        const int rk = cum + __popcll(em & lmask);
        cum += __popcll(em);
        const unsigned long long sel = gm[s2] | __ballot(e && (rk < need));
        if (s2 == 0) sb0 = sel; else if (s2 == 1) sb1 = sel;
        else if (s2 == 2) sb2 = sel; else sb3 = sel;
    }
    if (lane < 8) {
        const unsigned long long mv = (lane < 2) ? sb0 : (lane < 4) ? sb1
                                    : (lane < 6) ? sb2 : sb3;
        const unsigned int wd = (lane & 1) ? (unsigned int)(mv >> 32) : (unsigned int)mv;
        masks[(size_t)q * 8 + lane] = wd;
    }
}

// ---------------------------------------------------------------------------
// prep: VALU-bound route overlapped with memory-bound conversions (R4 layout).
//   blocks 0..3135      : top-49 route, queries 0..12543 (4/block, 1 wave ea)
//   next 784            : x fp32 -> bf16
//   next 192            : Wqkv -> WqkvT bf16 [1536][512]
//   next 28             : zero vT pad cols t=196..223
//   next 64             : Wv -> WvT bf16 [512][512]
// ---------------------------------------------------------------------------
__global__ __launch_bounds__(256) void prep(const float* __restrict__ x,
                                            const float* __restrict__ Wqkv,
                                            const float* __restrict__ Wv,
                                            const float* __restrict__ adj,
                                            unsigned short* __restrict__ xb,
                                            unsigned short* __restrict__ wqkvT,
                                            unsigned short* __restrict__ wvT,
                                            unsigned short* __restrict__ vT,
                                            unsigned int* __restrict__ masks) {
    __shared__ unsigned short Tt[64][72];
    const int t = threadIdx.x;
    const int bid = blockIdx.x;

    if (bid < QSPLIT_BLOCKS) {
        route_topk_q(adj, masks, bid * 4 + (t >> 6), t & 63);
        return;
    }
    int b2 = bid - QSPLIT_BLOCKS;
    if (b2 < 784) {
        const size_t base = ((size_t)b2 * 256 + t) * 8;
        const float4 v0 = *(const float4*)&x[base];
        const float4 v1 = *(const float4*)&x[base + 4];
        uint4 pk;
        pk.x = (unsigned int)f2bf(v0.x) | ((unsigned int)f2bf(v0.y) << 16);
        pk.y = (unsigned int)f2bf(v0.z) | ((unsigned int)f2bf(v0.w) << 16);
        pk.z = (unsigned int)f2bf(v1.x) | ((unsigned int)f2bf(v1.y) << 16);
        pk.w = (unsigned int)f2bf(v1.z) | ((unsigned int)f2bf(v1.w) << 16);
        *(uint4*)&xb[base] = pk;
        return;
    }
    b2 -= 784;
    if (b2 >= 192 && b2 < 220) {
        // zero vT pad cols t=196..223
        const int e0 = (b2 - 192) * 8192 + t;
#pragma unroll
        for (int i = 0; i < 32; ++i) {
            const int e = e0 + i * 256;          // 0..229375
            const int bh = e / 1792;             // 64*28
            const int rem = e - bh * 1792;
            const int d = rem / 28;
            const int tt = rem - d * 28;
            vT[(size_t)bh * (64 * 224) + (size_t)d * 224 + 196 + tt] = 0;
        }
        return;
    }

    // weight transposes via 64x64 LDS tile
    const float* src;
    unsigned short* dst;
    int Cc, tx, ty;
    if (b2 < 192) { src = Wqkv; dst = wqkvT; Cc = 1536; tx = b2 % 24; ty = b2 / 24; }
    else { const int b = b2 - 220; src = Wv; dst = wvT; Cc = 512; tx = b & 7; ty = b >> 3; }
    const int c0 = tx * 64, r0 = ty * 64;
#pragma unroll
    for (int p = 0; p < 4; ++p) {
        const int r = (t >> 4) + 16 * p;
        const int cl = (t & 15) * 4;
        const float4 v = *(const float4*)&src[(size_t)(r0 + r) * Cc + c0 + cl];
        Tt[cl + 0][r] = f2bf(v.x);
        Tt[cl + 1][r] = f2bf(v.y);
        Tt[cl + 2][r] = f2bf(v.z);
        Tt[cl + 3][r] = f2bf(v.w);
    }
    __syncthreads();
#pragma unroll
    for (int p = 0; p < 2; ++p) {
        const int cc = (t >> 3) + 32 * p;
        const int ch = (t & 7) * 8;
        *(uint4*)&dst[(size_t)(c0 + cc) * 512 + r0 + ch] = *(const uint4*)&Tt[cc][ch];
    }
}

// ---------------------------------------------------------------------------
// bf16 MFMA GEMM: C(MxN) = A(MxK) @ Bt(NxK)^T, fp32 accumulate.
// BMxBN tile, BK=32; 256 threads = 4 waves (2x2). Double-buffered
// global_load_lds. BM=64/BN=128 for gemm1 (MODE 1 scatter to q/k/vT, FUSE
// route); BM=32/BN=64 for gemm2 (784 blocks = 3.06/CU: tail-packed).
// ---------------------------------------------------------------------------
template <int BM, int BN, int MODE, int FUSE, typename CT>
__global__ __launch_bounds__(256) void gemm_mfma(const unsigned short* __restrict__ A,
                                                 const unsigned short* __restrict__ Bt,
                                                 CT* __restrict__ C,
                                                 const int M, const int N, const int K,
                                                 const float* __restrict__ adj,
                                                 unsigned int* __restrict__ masks) {
    constexpr int FN = BN / 32;       // N-frags per wave
    constexpr int MF = BM / 32;       // M-frags per wave
    constexpr int AW = BM / 16;       // waves staging the A tile
    constexpr int CSZ = (MODE == 1) ? 64 * 132 : 1;
    struct ABt { unsigned short A[BM][32]; unsigned short B[BN][32]; };
    __shared__ union {
        ABt ab[2];
        unsigned short Cs[CSZ];
    } sm;

    const int tid = threadIdx.x;
    const int lane = tid & 63, wid = tid >> 6;
    const int mt = M / BM;
    const int nGemm = mt * (N / BN);
    const int bid = blockIdx.x;

    if constexpr (FUSE) {
        if (bid >= nGemm) {
            const int rid = bid - nGemm;
            route_topk_q(adj, masks, QSPLIT_BLOCKS * 4 + rid * 4 + wid, lane);
            return;
        }
    }

    const int bx = bid % mt;          // consecutive blocks share the B panel
    const int by = bid / mt;
    const int row0 = bx * BM;
    const int col0 = by * BN;
    const int wr = wid >> 1, wc = wid & 1;

    f32x4 acc[MF][FN];
#pragma unroll
    for (int m = 0; m < MF; ++m)
#pragma unroll
        for (int n = 0; n < FN; ++n)
            acc[m][n] = (f32x4){0.0f, 0.0f, 0.0f, 0.0f};

    // per-lane staging sources: lane l covers row wid*16 + l/4, col (l%4)*8
    const int srow = lane >> 2;
    const int scol = (lane & 3) * 8;
    const unsigned short* aSrc = A + (size_t)(row0 + wid * 16 + srow) * K + scol;
    const unsigned short* bSrc = Bt + (size_t)(col0 + wid * 16 + srow) * K + scol;
    const unsigned short* bSrc2 = bSrc + (size_t)64 * K;

    const int fr = lane & 15;
    const int fk8 = (lane >> 4) * 8;

#define STAGE(BUF) do {                                                        \
        if (wid < AW) gload16(aSrc, &sm.ab[BUF].A[wid * 16][0]);               \
        gload16(bSrc, &sm.ab[BUF].B[wid * 16][0]);                             \
        if constexpr (BN == 128) gload16(bSrc2, &sm.ab[BUF].B[64 + wid * 16][0]); \
        aSrc += 32; bSrc += 32; bSrc2 += 32;                                   \
    } while (0)

#define COMPUTE(BUF) do {                                                      \
        bf16x8 af[MF], bfv[FN];                                                \
        _Pragma("unroll")                                                      \
        for (int m = 0; m < MF; ++m)                                           \
            af[m] = *(const bf16x8*)&sm.ab[BUF].A[wr * (BM / 2) + m * 16 + fr][fk8]; \
        _Pragma("unroll")                                                      \
        for (int n = 0; n < FN; ++n)                                           \
            bfv[n] = *(const bf16x8*)&sm.ab[BUF].B[wc * (BN / 2) + n * 16 + fr][fk8]; \
        _Pragma("unroll")                                                      \
        for (int m = 0; m < MF; ++m)                                           \
            _Pragma("unroll")                                                  \
            for (int n = 0; n < FN; ++n)                                       \
                acc[m][n] = __builtin_amdgcn_mfma_f32_16x16x32_bf16(af[m], bfv[n], acc[m][n], 0, 0, 0); \
    } while (0)

    STAGE(0);
    __syncthreads();

    for (int k0 = 0; k0 < K; k0 += 64) {
        if (k0 + 32 < K) STAGE(1);
        COMPUTE(0);
        __syncthreads();
        if (k0 + 64 < K) STAGE(0);
        COMPUTE(1);
        __syncthreads();
    }
#undef STAGE
#undef COMPUTE

    if constexpr (MODE == 0) {
#pragma unroll
        for (int m = 0; m < MF; ++m)
#pragma unroll
            for (int n = 0; n < FN; ++n)
#pragma unroll
                for (int i = 0; i < 4; ++i) {
                    const int row = row0 + wr * (BM / 2) + m * 16 + (lane >> 4) * 4 + i;
                    const int col = col0 + wc * (BN / 2) + n * 16 + (lane & 15);
                    C[(size_t)row * N + col] = (CT)acc[m][n][i];
                }
    } else {
        // ---- stage tile to LDS as bf16 (Cs overlays ab; safe after barrier) ----
#pragma unroll
        for (int m = 0; m < MF; ++m)
#pragma unroll
            for (int n = 0; n < FN; ++n)
#pragma unroll
                for (int i = 0; i < 4; ++i) {
                    const int rl = wr * (BM / 2) + m * 16 + (lane >> 4) * 4 + i;
                    const int cl = wc * (BN / 2) + n * 16 + (lane & 15);
                    sm.Cs[rl * 132 + cl] = f2bf(acc[m][n][i]);
                }
        __syncthreads();

        unsigned short* ubase = (unsigned short*)C;
#pragma unroll
        for (int ch = 0; ch < BN / 64; ++ch) {
            const int abscol = col0 + ch * 64;
            const int which = (abscol >> 6) % 3;
            const int hh = abscol / 192;
            if (which < 2) {
                // q/k: row-major [bh][196][64]; thread = (row, 16-col chunk)
                const int r = tid >> 2;
                const int co = (tid & 3) * 16;
                const int gr = row0 + r;
                const int bb = gr / T_;
                const int tt = gr - bb * T_;
                const uint2 a0 = *(const uint2*)&sm.Cs[r * 132 + ch * 64 + co];
                const uint2 a1 = *(const uint2*)&sm.Cs[r * 132 + ch * 64 + co + 4];
                const uint2 a2 = *(const uint2*)&sm.Cs[r * 132 + ch * 64 + co + 8];
                const uint2 a3 = *(const uint2*)&sm.Cs[r * 132 + ch * 64 + co + 12];
                unsigned short* dst = ubase + (size_t)which * KB_OFF +
                                      ((size_t)(bb * H_ + hh) * T_ + tt) * DHEAD_ + co;
                uint4 w0; w0.x = a0.x; w0.y = a0.y; w0.z = a1.x; w0.w = a1.y;
                uint4 w1; w1.x = a2.x; w1.y = a2.y; w1.z = a3.x; w1.w = a3.y;
                *(uint4*)&dst[0] = w0;
                *(uint4*)&dst[8] = w1;
            } else {
                // v: d-major [bh][64][224]; thread = (d, 16-row span)
                const int d = tid >> 2;
                const int j0 = (tid & 3) * 16;
                union { unsigned short s[16]; uint2 v2[4]; } tmp;
#pragma unroll
                for (int j = 0; j < 16; ++j)
                    tmp.s[j] = sm.Cs[(j0 + j) * 132 + ch * 64 + d];
                const int gr0 = row0 + j0;
                const int bb0 = gr0 / T_;
                const int bb1 = (gr0 + 15) / T_;
                if (bb0 == bb1) {
                    const int tt = gr0 - bb0 * T_;   // tt % 4 == 0 -> 8B aligned
                    unsigned short* dst = ubase + VT_OFF +
                                          (size_t)(bb0 * H_ + hh) * (64 * 224) +
                                          (size_t)d * 224 + tt;
                    *(uint2*)&dst[0]  = tmp.v2[0];
                    *(uint2*)&dst[4]  = tmp.v2[1];
                    *(uint2*)&dst[8]  = tmp.v2[2];
                    *(uint2*)&dst[12] = tmp.v2[3];
                } else {
#pragma unroll
                    for (int j = 0; j < 16; ++j) {
                        const int gr = gr0 + j;
                        const int bb = gr / T_;
                        const int tt = gr - bb * T_;
                        ubase[VT_OFF + (size_t)(bb * H_ + hh) * (64 * 224) +
                              (size_t)d * 224 + tt] = tmp.s[j];
                    }
                }
            }
        }
    }
}

// ---------------------------------------------------------------------------
// attn_mfma: dense masked attention. One 16-query tile per 256-thread block;
// the 13 key-chunks are SPLIT ACROSS THE 4 WAVES (4/3/3/3). Spill-free,
// grid (13,128)=1664 blocks = 6656 waves. (R4 version, best measured.)
// ---------------------------------------------------------------------------
__global__ __launch_bounds__(256, 4) void attn_mfma(const unsigned short* __restrict__ qb,
                                                    const unsigned short* __restrict__ kb,
                                                    const unsigned short* __restrict__ vT,
                                                    const unsigned int* __restrict__ masks,
                                                    unsigned short* __restrict__ obuf) {
    __shared__ union {
        struct { unsigned int mask[16][8]; unsigned short P[4][16][72]; } p1;
        struct { float Of[4][16][64]; float Lw[4][16]; } p2;
    } sm;

    const int tid = threadIdx.x;
    const int lane = tid & 63;
    const int w = tid >> 6;                 // wave 0..3
    const int qt = blockIdx.x;              // 0..12 (16-row tiles; tile 12: 4 valid)
    const int bh = blockIdx.y;              // 0..127
    const int bb = bh >> 3, hh = bh & 7;
    const int q0 = qt * 16;

    // masks (128 words) + zero own P[w][16][0..64)
    if (tid < 128) {
        const int r = tid >> 3, wd = tid & 7;
        const int t = q0 + r;
        sm.p1.mask[r][wd] = (t < T_) ? masks[((size_t)bh * T_ + t) * 8 + wd] : 0u;
    }
    {
        unsigned short* Pw = &sm.p1.P[w][0][0];
        const int r = lane >> 2, c = (lane & 3) * 16;
        *(uint4*)&Pw[r * 72 + c]     = (uint4){0u, 0u, 0u, 0u};
        *(uint4*)&Pw[r * 72 + c + 8] = (uint4){0u, 0u, 0u, 0u};
    }
    __syncthreads();

    const int fr = lane & 15;
    const int fk8 = (lane >> 4) * 8;
    const int nc = (w == 0) ? 4 : 3;
    const int cbase = (w == 0) ? 0 : 1 + 3 * w;     // 0,4,7,10
    const int keybase = cbase * 16;                  // 0,64,112,160

    const unsigned short* qbh = qb + ((size_t)bh * T_ + q0) * DHEAD_;
    const unsigned short* kbh = kb + (size_t)bh * T_ * DHEAD_;

    const bf16x8 aq0 = *(const bf16x8*)&qbh[fr * 64 + fk8];
    const bf16x8 aq1 = *(const bf16x8*)&qbh[fr * 64 + 32 + fk8];

    f32x4 s[4];
#pragma unroll
    for (int c2 = 0; c2 < 4; ++c2) s[c2] = (f32x4){0.0f, 0.0f, 0.0f, 0.0f};
    __builtin_amdgcn_s_setprio(1);
#pragma unroll
    for (int c2 = 0; c2 < 4; ++c2) {
        if (c2 < nc) {
            const int c = cbase + c2;
            const bf16x8 b0 = *(const bf16x8*)&kbh[(c * 16 + fr) * 64 + fk8];
            const bf16x8 b1 = *(const bf16x8*)&kbh[(c * 16 + fr) * 64 + 32 + fk8];
            s[c2] = __builtin_amdgcn_mfma_f32_16x16x32_bf16(aq0, b0, s[c2], 0, 0, 0);
            s[c2] = __builtin_amdgcn_mfma_f32_16x16x32_bf16(aq1, b1, s[c2], 0, 0, 0);
        }
    }
    __builtin_amdgcn_s_setprio(0);

    const float scale = 0.044194173824159216f;     // 512^-0.5
    float lv[4];
#pragma unroll
    for (int i = 0; i < 4; ++i) {
        const int rowl = (lane >> 4) * 4 + i;
        float li = 0.0f;
#pragma unroll
        for (int c2 = 0; c2 < 4; ++c2) {
            if (c2 < nc) {
                const int c = cbase + c2;
                const unsigned int mw = sm.p1.mask[rowl][c >> 1];
                const bool sel = (mw >> (((c & 1) << 4) + fr)) & 1u;
                const float pv = sel ? __expf(s[c2][i] * scale) : 0.0f;
                sm.p1.P[w][rowl][c2 * 16 + fr] = f2bf(pv);
                li += pv;
            }
        }
        lv[i] = li;
    }
#pragma unroll
    for (int off = 8; off >= 1; off >>= 1)
#pragma unroll
        for (int i = 0; i < 4; ++i)
            lv[i] += __shfl_xor(lv[i], off);

    // partial PV over this wave's 64-key window (keys beyond real range have P=0;
    // vT cols 196..223 are zeroed, window max col = keybase+63 <= 223)
    const unsigned short* vbh = vT + (size_t)bh * (64 * 224) + keybase;
    f32x4 o_p[4];
#pragma unroll
    for (int n = 0; n < 4; ++n) o_p[n] = (f32x4){0.0f, 0.0f, 0.0f, 0.0f};
    const bf16x8 ap0 = *(const bf16x8*)&sm.p1.P[w][fr][fk8];
    const bf16x8 ap1 = *(const bf16x8*)&sm.p1.P[w][fr][32 + fk8];
    __builtin_amdgcn_s_setprio(1);
#pragma unroll
    for (int n = 0; n < 4; ++n) {
        const bf16x8 bv0 = *(const bf16x8*)&vbh[(n * 16 + fr) * 224 + fk8];
        const bf16x8 bv1 = *(const bf16x8*)&vbh[(n * 16 + fr) * 224 + 32 + fk8];
        o_p[n] = __builtin_amdgcn_mfma_f32_16x16x32_bf16(ap0, bv0, o_p[n], 0, 0, 0);
        o_p[n] = __builtin_amdgcn_mfma_f32_16x16x32_bf16(ap1, bv1, o_p[n], 0, 0, 0);
    }
    __builtin_amdgcn_s_setprio(0);

    __syncthreads();   // all P reads done; safe to overwrite phase-1 LDS

    // write partial O (f32) + partial l
#pragma unroll
    for (int n = 0; n < 4; ++n)
#pragma unroll
        for (int i = 0; i < 4; ++i)
            sm.p2.Of[w][(lane >> 4) * 4 + i][n * 16 + fr] = o_p[n][i];
    if (fr == 0) {
#pragma unroll
        for (int i = 0; i < 4; ++i)
            sm.p2.Lw[w][(lane >> 4) * 4 + i] = lv[i];
    }
    __syncthreads();

    // combine + normalize + GELU + store: thread = (row, 4-col chunk)
    {
        const int r = tid >> 4;
        const int c0 = (tid & 15) * 4;
        const int t = q0 + r;
        if (t < T_) {
            const float l = sm.p2.Lw[0][r] + sm.p2.Lw[1][r] +
                            sm.p2.Lw[2][r] + sm.p2.Lw[3][r];
            const float rl = 1.0f / l;
            const f32x4 a0 = *(const f32x4*)&sm.p2.Of[0][r][c0];
            const f32x4 a1 = *(const f32x4*)&sm.p2.Of[1][r][c0];
            const f32x4 a2 = *(const f32x4*)&sm.p2.Of[2][r][c0];
            const f32x4 a3 = *(const f32x4*)&sm.p2.Of[3][r][c0];
            union { unsigned short s[4]; unsigned long long u; } pk;
#pragma unroll
            for (int j = 0; j < 4; ++j) {
                const float ov = (a0[j] + a1[j] + a2[j] + a3[j]) * rl;
                const float g = 0.5f * ov * (1.0f + erff(ov * 0.70710678118654752f));
                pk.s[j] = f2bf(g);
            }
            unsigned short* orow = obuf + ((size_t)(bb * T_ + t)) * DIM_ +
                                   hh * DHEAD_ + c0;
            *(unsigned long long*)orow = pk.u;
        }
    }
}

extern "C" void kernel_launch(void* const* d_in, const int* in_sizes, int n_in,
                              void* d_out, int out_size, void* d_ws, size_t ws_size,
                              hipStream_t stream) {
    const float* x    = (const float*)d_in[0];
    const float* adj  = (const float*)d_in[1];
    const float* Wqkv = (const float*)d_in[2];
    const float* Wv   = (const float*)d_in[3];
    float* out = (float*)d_out;
    unsigned short* ub = (unsigned short*)d_ws;

    unsigned short* qb    = ub + QB_OFF;
    unsigned short* kb    = ub + KB_OFF;
    unsigned short* vT    = ub + VT_OFF;
    unsigned short* xb    = ub + XB_OFF;      // x bf16; reused as o bf16
    unsigned short* wqkvT = ub + WQKVT_OFF;
    unsigned short* wvT   = ub + WVT_OFF;
    unsigned int*   masks = (unsigned int*)(ub + MASK_OFF);

    // 0) route queries 0..12543 (VALU) + x/Wqkv/Wv conversions (memory) + vT pad
    prep<<<4204, 256, 0, stream>>>(x, Wqkv, Wv, adj, xb, wqkvT, wvT, vT, masks);

    // 1) qkv = x @ Wqkv (BM=64/BN=128: 588 blocks) + route 12544..25087
    gemm_mfma<64, 128, 1, 1, unsigned short><<<3724, 256, 0, stream>>>(
        xb, wqkvT, ub, BT_, 3 * DIM_, DIM_, adj, masks);

    // 2) dense masked attention + gelu -> o bf16 (aliases xb); K-split 4-wave
    attn_mfma<<<dim3(13, BH_), 256, 0, stream>>>(qb, kb, vT, masks, xb);

    // 3) out = o @ Wv (BM=32/BN=64: 98x8 = 784 blocks, 3.06/CU tail-packed)
    gemm_mfma<32, 64, 0, 0, float><<<784, 256, 0, stream>>>(
        xb, wvT, out, BT_, DIM_, DIM_, nullptr, nullptr);
}